// Round 4
// baseline (141.667 us; speedup 1.0000x reference)
//
#include <hip/hip_runtime.h>
#include <hip/hip_bf16.h>

#define B_   128
#define LSEQ 8194
#define NPOS 2048

typedef __attribute__((ext_vector_type(8))) short bf16x8;
typedef __attribute__((ext_vector_type(4))) float f32x4;

static __device__ __forceinline__ short f2bf(float f){
    union { __hip_bfloat16 h; short s; } u; u.h = __float2bfloat16(f); return u.s;
}
static __device__ __forceinline__ float tanh_fast(float x){
    float ex = __expf(2.0f * x);
    return 1.0f - __fdividef(2.0f, ex + 1.0f);
}

// build per-letter tap tables: tbl[t][l][cp] = (emb[l].cw[2cp,:,t], emb[l].cw[2cp+1,:,t])
static __device__ __forceinline__ void build_tbl(float2 (*tbl)[26][17],
        const float* __restrict__ emb, const float* __restrict__ cw,
        const float* __restrict__ cb, int tid)
{
    for (int idx = tid; idx < 3*26*16; idx += 256){
        int k = idx / (26*16);
        int rem = idx - k*26*16;
        int l = rem >> 4;
        int cp = rem & 15;
        int c0 = cp*2;
        float v0 = 0.f, v1 = 0.f;
        #pragma unroll
        for (int i = 0; i < 5; i++){
            float e = emb[l*5 + i];
            v0 += cw[(c0*5 + i)*3 + k] * e;
            v1 += cw[((c0+1)*5 + i)*3 + k] * e;
        }
        if (k == 2){ v0 += cb[c0]; v1 += cb[c0+1]; }
        tbl[k][l][cp] = make_float2(v0, v1);
    }
}

// KA: fused conv + attention-GEMM -> e[b,n]. B-frags generated DIRECTLY in
// registers (generation lane == consumption lane); no LDS y2 tile, no
// barriers in the main loop. Block = 256-n chunk (4 sub-tiles of 64 rows).
__global__ __launch_bounds__(256, 2) void ka_conv_gemm(
        const int* __restrict__ seq, const float* __restrict__ emb,
        const float* __restrict__ cw, const float* __restrict__ cb,
        const float* __restrict__ Wa, const float* __restrict__ va,
        float* __restrict__ ws_e)
{
    __shared__ float2 tbl[3][26][17];   // pad 17: spreads letter-gather banks
    __shared__ int    seqw[4][260];     // 4 section windows of 258 letters
    __shared__ float  va_lds[128];

    int tid = threadIdx.x;
    int b   = blockIdx.y;
    int n0  = blockIdx.x * 256;

    if (tid < 128) va_lds[tid] = va[tid];
    build_tbl(tbl, emb, cw, cb, tid);
    const int* sb = seq + (size_t)b * LSEQ;
    for (int i = tid; i < 4*258; i += 256){
        int s = i / 258, off = i - s*258;
        seqw[s][off] = sb[s*2048 + n0 + off];
    }

    int wave = tid >> 6, lane = tid & 63;
    int m = lane & 15, q = lane >> 4;

    // W_a A-fragments in registers: lane holds W[dt*16+m][ki*32 + q*8 + j]
    bf16x8 wf[8][4];
    #pragma unroll
    for (int dt = 0; dt < 8; dt++){
        #pragma unroll
        for (int ki = 0; ki < 4; ki++){
            const float* wp = Wa + (dt*16 + m)*128 + ki*32 + q*8;
            float4 a  = *((const float4*)wp);
            float4 b4 = *((const float4*)(wp + 4));
            bf16x8 f;
            f[0]=f2bf(a.x);  f[1]=f2bf(a.y);  f[2]=f2bf(a.z);  f[3]=f2bf(a.w);
            f[4]=f2bf(b4.x); f[5]=f2bf(b4.y); f[6]=f2bf(b4.z); f[7]=f2bf(b4.w);
            wf[dt][ki] = f;
        }
    }
    __syncthreads();   // tbl, seqw, va ready; no barriers after this

    for (int sub = 0; sub < 4; sub++){
        int row = sub*64 + wave*16 + m;   // local n this lane generates & consumes
        // per-(section,tap) table pointers; ki becomes an immediate ds offset
        const float2* p0[4]; const float2* p1[4]; const float2* p2[4];
        #pragma unroll
        for (int s = 0; s < 4; s++){
            p0[s] = &tbl[0][seqw[s][row  ]][q];
            p1[s] = &tbl[1][seqw[s][row+1]][q];
            p2[s] = &tbl[2][seqw[s][row+2]][q];
        }
        f32x4 acc[8];
        #pragma unroll
        for (int dt = 0; dt < 8; dt++) acc[dt] = (f32x4){0.f,0.f,0.f,0.f};
        #pragma unroll
        for (int ki = 0; ki < 4; ki++){
            float res[8];
            #pragma unroll
            for (int s = 0; s < 4; s++){
                float2 g0 = p0[s][ki*4];
                float2 g1 = p1[s][ki*4];
                float2 g2 = p2[s][ki*4];
                res[s]   = fmaxf(g0.x + g1.x + g2.x, 0.f);  // k = cp*8+s
                res[4+s] = fmaxf(g0.y + g1.y + g2.y, 0.f);  // k = cp*8+4+s
            }
            bf16x8 bfrag;
            #pragma unroll
            for (int j = 0; j < 8; j++) bfrag[j] = f2bf(res[j]);
            #pragma unroll
            for (int dt = 0; dt < 8; dt++)
                acc[dt] = __builtin_amdgcn_mfma_f32_16x16x32_bf16(wf[dt][ki], bfrag, acc[dt], 0, 0, 0);
        }
        // epilogue: e[n] = sum_d va[d]*tanh(z[d][n]); lane holds d = dt*16+q*4+r, n = lane&15
        float epart = 0.f;
        #pragma unroll
        for (int dt = 0; dt < 8; dt++){
            float4 vv = *((const float4*)&va_lds[dt*16 + q*4]);
            epart += vv.x * tanh_fast(acc[dt][0]);
            epart += vv.y * tanh_fast(acc[dt][1]);
            epart += vv.z * tanh_fast(acc[dt][2]);
            epart += vv.w * tanh_fast(acc[dt][3]);
        }
        epart += __shfl_xor(epart, 16);
        epart += __shfl_xor(epart, 32);
        if (lane < 16)
            ws_e[b*NPOS + n0 + sub*64 + wave*16 + lane] = epart;
    }
}

// KB1: partial weighted pool per (b, 256-n chunk). Softmax stats recomputed
// redundantly per block (cheap); y2 regenerated fp32 from tables.
// part[(b*8+x)*128 + d] written exactly once. No atomics.
__global__ __launch_bounds__(256) void kb1_pool(
        const int* __restrict__ seq, const float* __restrict__ emb,
        const float* __restrict__ cw, const float* __restrict__ cb,
        const float* __restrict__ ws_e, float* __restrict__ part)
{
    __shared__ float2 tbl[3][26][17];
    __shared__ int    seqw[4][260];
    __shared__ float  wlds[256];
    __shared__ float  red[4], red2[4];
    __shared__ float  red3[4][16][8];

    int tid = threadIdx.x;
    int b = blockIdx.y;
    int x = blockIdx.x;
    int n0 = x * 256;

    build_tbl(tbl, emb, cw, cb, tid);
    const int* sb = seq + (size_t)b * LSEQ;
    for (int i = tid; i < 4*258; i += 256){
        int s = i / 258, off = i - s*258;
        seqw[s][off] = sb[s*2048 + n0 + off];
    }

    // softmax stats over the full e row
    const float* e = ws_e + b*NPOS;
    float ev[8];
    #pragma unroll
    for (int r = 0; r < 8; r++) ev[r] = e[tid + r*256];
    int wave = tid >> 6, lane = tid & 63;
    float mx = -1e30f;
    #pragma unroll
    for (int r = 0; r < 8; r++) mx = fmaxf(mx, ev[r]);
    #pragma unroll
    for (int off = 32; off >= 1; off >>= 1) mx = fmaxf(mx, __shfl_xor(mx, off));
    if (lane == 0) red[wave] = mx;
    __syncthreads();
    mx = fmaxf(fmaxf(red[0], red[1]), fmaxf(red[2], red[3]));
    float sum = 0.f;
    #pragma unroll
    for (int r = 0; r < 8; r++) sum += __expf(ev[r] - mx);
    #pragma unroll
    for (int off = 32; off >= 1; off >>= 1) sum += __shfl_xor(sum, off);
    if (lane == 0) red2[wave] = sum;
    __syncthreads();
    float rs = 1.0f / (red2[0] + red2[1] + red2[2] + red2[3]);
    wlds[tid] = __expf(e[n0 + tid] - mx) * rs;   // this chunk's weights
    __syncthreads();

    // pool: thread (g = tid&15 -> cp, nn = tid>>4) over n = it*16+nn
    int g = tid & 15, nn = tid >> 4;
    float acc[8] = {0,0,0,0,0,0,0,0};
    for (int it = 0; it < 16; it++){
        int n = it*16 + nn;
        float wgt = wlds[n];
        #pragma unroll
        for (int s = 0; s < 4; s++){
            int l1 = seqw[s][n], l2 = seqw[s][n+1], l3 = seqw[s][n+2];
            float2 g0 = tbl[0][l1][g];
            float2 g1 = tbl[1][l2][g];
            float2 g2 = tbl[2][l3][g];
            acc[s]   += wgt * fmaxf(g0.x + g1.x + g2.x, 0.f);
            acc[4+s] += wgt * fmaxf(g0.y + g1.y + g2.y, 0.f);
        }
    }
    // reduce over nn (lane bits 4,5 then cross-wave)
    #pragma unroll
    for (int j = 0; j < 8; j++){
        acc[j] += __shfl_xor(acc[j], 16);
        acc[j] += __shfl_xor(acc[j], 32);
    }
    if (lane < 16){
        #pragma unroll
        for (int j = 0; j < 8; j++) red3[wave][lane][j] = acc[j];
    }
    __syncthreads();
    if (tid < 128){
        int gg = tid >> 3, jj = tid & 7;
        part[((size_t)b*8 + x)*128 + tid] =
            red3[0][gg][jj] + red3[1][gg][jj] + red3[2][gg][jj] + red3[3][gg][jj];
    }
}

// KB2: out[b][d] = sum_x part[b][x][d] — deterministic direct store
__global__ __launch_bounds__(128) void kb2_finish(const float* __restrict__ part,
        float* __restrict__ out)
{
    int b = blockIdx.x, d = threadIdx.x;
    const float* p = part + (size_t)b*8*128 + d;
    float s = 0.f;
    #pragma unroll
    for (int x = 0; x < 8; x++) s += p[x*128];
    out[b*128 + d] = s;
}

extern "C" void kernel_launch(void* const* d_in, const int* in_sizes, int n_in,
                              void* d_out, int out_size, void* d_ws, size_t ws_size,
                              hipStream_t stream)
{
    const int*   seq = (const int*)d_in[0];
    const float* emb = (const float*)d_in[1];
    const float* cw  = (const float*)d_in[2];
    const float* cb  = (const float*)d_in[3];
    const float* Wa  = (const float*)d_in[4];
    const float* va  = (const float*)d_in[5];
    float* out = (float*)d_out;

    float* ws_e  = (float*)d_ws;                               // 128*2048 f32 = 1 MiB
    float* part  = (float*)((char*)d_ws + (size_t)1048576);    // 128*8*128 f32 = 512 KiB

    ka_conv_gemm<<<dim3(8,128), 256, 0, stream>>>(seq, emb, cw, cb, Wa, va, ws_e);
    kb1_pool    <<<dim3(8,128), 256, 0, stream>>>(seq, emb, cw, cb, ws_e, part);
    kb2_finish  <<<128,         128, 0, stream>>>(part, out);
}

// Round 5
// 131.949 us; speedup vs baseline: 1.0736x; 1.0736x over previous
//
#include <hip/hip_runtime.h>
#include <hip/hip_bf16.h>

#define B_   128
#define LSEQ 8194
#define NPOS 2048

typedef __attribute__((ext_vector_type(8))) short bf16x8;
typedef __attribute__((ext_vector_type(4))) float f32x4;

static __device__ __forceinline__ short f2bf(float f){
    union { __hip_bfloat16 h; short s; } u; u.h = __float2bfloat16(f); return u.s;
}
static __device__ __forceinline__ unsigned pack_bf2(float a, float b){
    union { __hip_bfloat162 h; unsigned u; } u;
    u.h = __float22bfloat162_rn(make_float2(a, b));
    return u.u;
}
static __device__ __forceinline__ float bflo(unsigned u){
    union { float f; unsigned u; } x; x.u = u << 16; return x.f;
}
static __device__ __forceinline__ float bfhi(unsigned u){
    union { float f; unsigned u; } x; x.u = u & 0xffff0000u; return x.f;
}
static __device__ __forceinline__ float tanh_fast(float x){
    float ex = __expf(2.0f * x);
    return 1.0f - __fdividef(2.0f, ex + 1.0f);
}

// per-letter tap tables, bf162-packed, stride 17 DWORDS (odd -> letters spread
// over all 32 banks; b32 gather = 1 bank-touch/lane, ~conflict-free).
// tblb[t][l][cp] packs channels (2cp, 2cp+1); bias folded into tap 2.
static __device__ __forceinline__ void build_tbl(unsigned (*tblb)[26][17],
        const float* __restrict__ emb, const float* __restrict__ cw,
        const float* __restrict__ cb, int tid)
{
    for (int idx = tid; idx < 3*26*16; idx += 256){
        int k = idx / (26*16);
        int rem = idx - k*26*16;
        int l = rem >> 4;
        int cp = rem & 15;
        int c0 = cp*2;
        float v0 = 0.f, v1 = 0.f;
        #pragma unroll
        for (int i = 0; i < 5; i++){
            float e = emb[l*5 + i];
            v0 += cw[(c0*5 + i)*3 + k] * e;
            v1 += cw[((c0+1)*5 + i)*3 + k] * e;
        }
        if (k == 2){ v0 += cb[c0]; v1 += cb[c0+1]; }
        tblb[k][l][cp] = pack_bf2(v0, v1);
    }
}

// KA: fused conv + attention-GEMM -> e[b,n]. B-frags generated directly in
// registers (generation lane == consumption lane); no main-loop barriers.
// Block = 512-n chunk, 8 sub-tiles of 64 rows. Grid (4,128) = 2 blocks/CU.
__global__ __launch_bounds__(256, 2) void ka_conv_gemm(
        const int* __restrict__ seq, const float* __restrict__ emb,
        const float* __restrict__ cw, const float* __restrict__ cb,
        const float* __restrict__ Wa, const float* __restrict__ va,
        float* __restrict__ ws_e)
{
    __shared__ unsigned tblb[3][26][17];
    __shared__ int      seqw[4][516];     // 4 section windows of 514 letters
    __shared__ float    va_lds[128];

    int tid = threadIdx.x;
    int b   = blockIdx.y;
    int n0  = blockIdx.x * 512;

    if (tid < 128) va_lds[tid] = va[tid];
    build_tbl(tblb, emb, cw, cb, tid);
    const int* sb = seq + (size_t)b * LSEQ;
    for (int i = tid; i < 4*514; i += 256){
        int s = i / 514, off = i - s*514;
        seqw[s][off] = sb[s*2048 + n0 + off];
    }

    int wave = tid >> 6, lane = tid & 63;
    int m = lane & 15, q = lane >> 4;

    // W_a A-fragments in registers: lane holds W[dt*16+m][ki*32 + q*8 + j]
    bf16x8 wf[8][4];
    #pragma unroll
    for (int dt = 0; dt < 8; dt++){
        #pragma unroll
        for (int ki = 0; ki < 4; ki++){
            const float* wp = Wa + (dt*16 + m)*128 + ki*32 + q*8;
            float4 a  = *((const float4*)wp);
            float4 b4 = *((const float4*)(wp + 4));
            bf16x8 f;
            f[0]=f2bf(a.x);  f[1]=f2bf(a.y);  f[2]=f2bf(a.z);  f[3]=f2bf(a.w);
            f[4]=f2bf(b4.x); f[5]=f2bf(b4.y); f[6]=f2bf(b4.z); f[7]=f2bf(b4.w);
            wf[dt][ki] = f;
        }
    }
    __syncthreads();   // tbl, seqw, va ready; no barriers after this

    for (int sub = 0; sub < 8; sub++){
        int row = sub*64 + wave*16 + m;   // local n this lane generates & consumes
        // per-(section,tap) base pointers at cp = q; ki adds an immediate offset
        const unsigned *p0[4], *p1[4], *p2[4];
        #pragma unroll
        for (int s = 0; s < 4; s++){
            p0[s] = &tblb[0][seqw[s][row  ]][q];
            p1[s] = &tblb[1][seqw[s][row+1]][q];
            p2[s] = &tblb[2][seqw[s][row+2]][q];
        }
        f32x4 acc[8];
        #pragma unroll
        for (int dt = 0; dt < 8; dt++) acc[dt] = (f32x4){0.f,0.f,0.f,0.f};
        #pragma unroll
        for (int ki = 0; ki < 4; ki++){
            float res[8];
            #pragma unroll
            for (int s = 0; s < 4; s++){
                unsigned u0 = p0[s][ki*4];
                unsigned u1 = p1[s][ki*4];
                unsigned u2 = p2[s][ki*4];
                res[s]   = fmaxf(bflo(u0) + bflo(u1) + bflo(u2), 0.f);  // c=2cp,   k=cp*8+s
                res[4+s] = fmaxf(bfhi(u0) + bfhi(u1) + bfhi(u2), 0.f);  // c=2cp+1, k=cp*8+4+s
            }
            bf16x8 bfrag;
            #pragma unroll
            for (int j = 0; j < 8; j++) bfrag[j] = f2bf(res[j]);
            #pragma unroll
            for (int dt = 0; dt < 8; dt++)
                acc[dt] = __builtin_amdgcn_mfma_f32_16x16x32_bf16(wf[dt][ki], bfrag, acc[dt], 0, 0, 0);
        }
        // e[n] = sum_d va[d]*tanh(z[d][n]); lane holds d = dt*16+q*4+r, n = lane&15
        float epart = 0.f;
        #pragma unroll
        for (int dt = 0; dt < 8; dt++){
            float4 vv = *((const float4*)&va_lds[dt*16 + q*4]);
            epart += vv.x * tanh_fast(acc[dt][0]);
            epart += vv.y * tanh_fast(acc[dt][1]);
            epart += vv.z * tanh_fast(acc[dt][2]);
            epart += vv.w * tanh_fast(acc[dt][3]);
        }
        epart += __shfl_xor(epart, 16);
        epart += __shfl_xor(epart, 32);
        if (lane < 16)
            ws_e[b*NPOS + n0 + sub*64 + wave*16 + lane] = epart;
    }
}

// KB1: partial weighted pool per (b, 256-n chunk). Softmax stats recomputed
// redundantly per block; y2 regenerated from the bf162 tables.
// part[(b*8+x)*128 + d] written exactly once. No atomics, no out pre-state.
__global__ __launch_bounds__(256) void kb1_pool(
        const int* __restrict__ seq, const float* __restrict__ emb,
        const float* __restrict__ cw, const float* __restrict__ cb,
        const float* __restrict__ ws_e, float* __restrict__ part)
{
    __shared__ unsigned tblb[3][26][17];
    __shared__ int      seqw[4][260];
    __shared__ float    wlds[256];
    __shared__ float    red[4], red2[4];
    __shared__ float    red3[4][16][8];

    int tid = threadIdx.x;
    int b = blockIdx.y;
    int x = blockIdx.x;
    int n0 = x * 256;

    build_tbl(tblb, emb, cw, cb, tid);
    const int* sb = seq + (size_t)b * LSEQ;
    for (int i = tid; i < 4*258; i += 256){
        int s = i / 258, off = i - s*258;
        seqw[s][off] = sb[s*2048 + n0 + off];
    }

    // softmax stats over the full e row
    const float* e = ws_e + b*NPOS;
    float ev[8];
    #pragma unroll
    for (int r = 0; r < 8; r++) ev[r] = e[tid + r*256];
    int wave = tid >> 6, lane = tid & 63;
    float mx = -1e30f;
    #pragma unroll
    for (int r = 0; r < 8; r++) mx = fmaxf(mx, ev[r]);
    #pragma unroll
    for (int off = 32; off >= 1; off >>= 1) mx = fmaxf(mx, __shfl_xor(mx, off));
    if (lane == 0) red[wave] = mx;
    __syncthreads();
    mx = fmaxf(fmaxf(red[0], red[1]), fmaxf(red[2], red[3]));
    float sum = 0.f;
    #pragma unroll
    for (int r = 0; r < 8; r++) sum += __expf(ev[r] - mx);
    #pragma unroll
    for (int off = 32; off >= 1; off >>= 1) sum += __shfl_xor(sum, off);
    if (lane == 0) red2[wave] = sum;
    __syncthreads();
    float rs = 1.0f / (red2[0] + red2[1] + red2[2] + red2[3]);
    wlds[tid] = __expf(e[n0 + tid] - mx) * rs;   // this chunk's weights
    __syncthreads();

    // pool: thread (g = tid&15 -> cp, nn = tid>>4) over n = it*16+nn
    int g = tid & 15, nn = tid >> 4;
    float acc[8] = {0,0,0,0,0,0,0,0};
    for (int it = 0; it < 16; it++){
        int n = it*16 + nn;
        float wgt = wlds[n];
        #pragma unroll
        for (int s = 0; s < 4; s++){
            unsigned u0 = tblb[0][seqw[s][n  ]][g];
            unsigned u1 = tblb[1][seqw[s][n+1]][g];
            unsigned u2 = tblb[2][seqw[s][n+2]][g];
            acc[s]   += wgt * fmaxf(bflo(u0) + bflo(u1) + bflo(u2), 0.f);
            acc[4+s] += wgt * fmaxf(bfhi(u0) + bfhi(u1) + bfhi(u2), 0.f);
        }
    }
    // reduce over nn (lane bits 4,5 then cross-wave via LDS)
    #pragma unroll
    for (int j = 0; j < 8; j++){
        acc[j] += __shfl_xor(acc[j], 16);
        acc[j] += __shfl_xor(acc[j], 32);
    }
    if (lane < 16){
        #pragma unroll
        for (int j = 0; j < 8; j++) red3[wave][lane][j] = acc[j];
    }
    __syncthreads();
    if (tid < 128){
        int gg = tid >> 3, jj = tid & 7;
        part[((size_t)b*8 + x)*128 + tid] =
            red3[0][gg][jj] + red3[1][gg][jj] + red3[2][gg][jj] + red3[3][gg][jj];
    }
}

// KB2: out[b][d] = sum_x part[b][x][d] — deterministic direct store
__global__ __launch_bounds__(128) void kb2_finish(const float* __restrict__ part,
        float* __restrict__ out)
{
    int b = blockIdx.x, d = threadIdx.x;
    const float* p = part + (size_t)b*8*128 + d;
    float s = 0.f;
    #pragma unroll
    for (int x = 0; x < 8; x++) s += p[x*128];
    out[b*128 + d] = s;
}

extern "C" void kernel_launch(void* const* d_in, const int* in_sizes, int n_in,
                              void* d_out, int out_size, void* d_ws, size_t ws_size,
                              hipStream_t stream)
{
    const int*   seq = (const int*)d_in[0];
    const float* emb = (const float*)d_in[1];
    const float* cw  = (const float*)d_in[2];
    const float* cb  = (const float*)d_in[3];
    const float* Wa  = (const float*)d_in[4];
    const float* va  = (const float*)d_in[5];
    float* out = (float*)d_out;

    float* ws_e  = (float*)d_ws;                               // 128*2048 f32 = 1 MiB
    float* part  = (float*)((char*)d_ws + (size_t)1048576);    // 128*8*128 f32 = 512 KiB

    ka_conv_gemm<<<dim3(4,128), 256, 0, stream>>>(seq, emb, cw, cb, Wa, va, ws_e);
    kb1_pool    <<<dim3(8,128), 256, 0, stream>>>(seq, emb, cw, cb, ws_e, part);
    kb2_finish  <<<128,         128, 0, stream>>>(part, out);
}

// Round 6
// 127.206 us; speedup vs baseline: 1.1137x; 1.0373x over previous
//
#include <hip/hip_runtime.h>
#include <hip/hip_bf16.h>

#define B_   128
#define LSEQ 8194
#define NPOS 2048

typedef __attribute__((ext_vector_type(8))) short bf16x8;
typedef __attribute__((ext_vector_type(4))) float f32x4;

static __device__ __forceinline__ short f2bf(float f){
    union { __hip_bfloat16 h; short s; } u; u.h = __float2bfloat16(f); return u.s;
}
static __device__ __forceinline__ float tanh_fast(float x){
    float ex = __expf(2.0f * x);
    return 1.0f - __fdividef(2.0f, ex + 1.0f);
}
// pack two f32 -> bf16x2 dword (round-half-up): low16 = bf16(a), high16 = bf16(b)
static __device__ __forceinline__ unsigned bpack(float a, float b){
    unsigned ua = __float_as_uint(a) + 0x8000u;
    unsigned ub = __float_as_uint(b) + 0x8000u;
    return __builtin_amdgcn_perm(ub, ua, 0x07060302u);   // dst[1:0]=ua[3:2], dst[3:2]=ub[3:2]
}

// KA: fused conv + attention-GEMM -> e[b,n].
// Per block: 256 n-positions, 4 sub-tiles of 64 rows.
// Wave w owns d-dims [32w,32w+32) (wf[2][4] = 32 VGPRs) -> 4 waves/SIMD.
// B-frags generated from permuted f32 tap tables (1 ds_read_b128 = 4 ki vals),
// shared across waves via a 16KB LDS tile.
__global__ __launch_bounds__(256, 4) void ka_conv_gemm(
        const int* __restrict__ seq, const float* __restrict__ emb,
        const float* __restrict__ cw, const float* __restrict__ cb,
        const float* __restrict__ Wa, const float* __restrict__ va,
        float* __restrict__ ws_e)
{
    __shared__ float tblA[3][26][20];   // [tap][letter][perm pos], ch even; stride 20 dw
    __shared__ float tblB[3][26][20];   // ch odd
    __shared__ int   seqw[4][260];      // 4 section windows of 258 letters
    __shared__ uint4 bshare[16*64];     // [(rg*4+ki)*64 + lane] B-frags
    __shared__ float epar[4][64];       // per-wave e partials

    int tid = threadIdx.x;
    int b   = blockIdx.y;
    int n0  = blockIdx.x * 256;

    // permuted f32 tap tables: pos p=(cp&3)*4+(cp>>2) holds channel pair (2cp,2cp+1)
    for (int idx = tid; idx < 3*26*16; idx += 256){
        int k = idx / (26*16);
        int rem = idx - k*26*16;
        int l = rem >> 4;
        int cp = rem & 15;
        int c0 = cp*2;
        float v0 = 0.f, v1 = 0.f;
        #pragma unroll
        for (int i = 0; i < 5; i++){
            float e = emb[l*5 + i];
            v0 += cw[(c0*5 + i)*3 + k] * e;
            v1 += cw[((c0+1)*5 + i)*3 + k] * e;
        }
        if (k == 2){ v0 += cb[c0]; v1 += cb[c0+1]; }
        int p = (cp & 3)*4 + (cp >> 2);
        tblA[k][l][p] = v0;
        tblB[k][l][p] = v1;
    }
    const int* sb = seq + (size_t)b * LSEQ;
    for (int i = tid; i < 4*258; i += 256){
        int s = i / 258, off = i - s*258;
        seqw[s][off] = sb[s*2048 + n0 + off];
    }

    int w = tid >> 6, lane = tid & 63;
    int m = lane & 15, q = lane >> 4;

    // wave w's W_a A-frags: dt_glob = 2w+dtL; lane holds W[dt_glob*16+m][ki*32+q*8+j]
    bf16x8 wf[2][4];
    #pragma unroll
    for (int dtL = 0; dtL < 2; dtL++){
        #pragma unroll
        for (int ki = 0; ki < 4; ki++){
            const float* wp = Wa + ((2*w+dtL)*16 + m)*128 + ki*32 + q*8;
            float4 a  = *((const float4*)wp);
            float4 b4 = *((const float4*)(wp + 4));
            bf16x8 f;
            f[0]=f2bf(a.x);  f[1]=f2bf(a.y);  f[2]=f2bf(a.z);  f[3]=f2bf(a.w);
            f[4]=f2bf(b4.x); f[5]=f2bf(b4.y); f[6]=f2bf(b4.z); f[7]=f2bf(b4.w);
            wf[dtL][ki] = f;
        }
    }
    // va values this lane's acc elements map to: d = (2w+dtL)*16 + q*4 + r
    float varg[2][4];
    #pragma unroll
    for (int dtL = 0; dtL < 2; dtL++){
        #pragma unroll
        for (int r = 0; r < 4; r++)
            varg[dtL][r] = va[(2*w+dtL)*16 + q*4 + r];
    }
    __syncthreads();

    for (int sub = 0; sub < 4; sub++){
        // --- gen: wave w produces B-frags for rows [sub*64 + w*16, +16) ---
        int row = sub*64 + w*16 + m;
        float4 VA[4], VB[4];
        #pragma unroll
        for (int s = 0; s < 4; s++){
            int l0 = seqw[s][row], l1 = seqw[s][row+1], l2 = seqw[s][row+2];
            float4 a0 = *((const float4*)&tblA[0][l0][q*4]);
            float4 a1 = *((const float4*)&tblA[1][l1][q*4]);
            float4 a2 = *((const float4*)&tblA[2][l2][q*4]);
            float4 b0 = *((const float4*)&tblB[0][l0][q*4]);
            float4 b1 = *((const float4*)&tblB[1][l1][q*4]);
            float4 b2 = *((const float4*)&tblB[2][l2][q*4]);
            VA[s].x = fmaxf(a0.x+a1.x+a2.x, 0.f); VA[s].y = fmaxf(a0.y+a1.y+a2.y, 0.f);
            VA[s].z = fmaxf(a0.z+a1.z+a2.z, 0.f); VA[s].w = fmaxf(a0.w+a1.w+a2.w, 0.f);
            VB[s].x = fmaxf(b0.x+b1.x+b2.x, 0.f); VB[s].y = fmaxf(b0.y+b1.y+b2.y, 0.f);
            VB[s].z = fmaxf(b0.z+b1.z+b2.z, 0.f); VB[s].w = fmaxf(b0.w+b1.w+b2.w, 0.f);
        }
        // pack per ki (float4 element ki) and write to bshare
        {
            const float* fA = (const float*)VA;   // fA[s*4+ki]
            const float* fB = (const float*)VB;
            #pragma unroll
            for (int ki = 0; ki < 4; ki++){
                uint4 o;
                o.x = bpack(fA[ki], fA[4+ki]);      // (ch0,s0),(ch0,s1)
                o.y = bpack(fA[8+ki], fA[12+ki]);   // (ch0,s2),(ch0,s3)
                o.z = bpack(fB[ki], fB[4+ki]);      // (ch1,s0),(ch1,s1)
                o.w = bpack(fB[8+ki], fB[12+ki]);   // (ch1,s2),(ch1,s3)
                bshare[(w*4 + ki)*64 + lane] = o;
            }
        }
        __syncthreads();   // bshare ready

        // --- MFMA: wave w computes z[32w..32w+31][all 64 rows] ---
        f32x4 acc[2][4];
        #pragma unroll
        for (int dtL = 0; dtL < 2; dtL++)
            #pragma unroll
            for (int rg = 0; rg < 4; rg++) acc[dtL][rg] = (f32x4){0.f,0.f,0.f,0.f};
        #pragma unroll
        for (int rg = 0; rg < 4; rg++){
            #pragma unroll
            for (int ki = 0; ki < 4; ki++){
                uint4 u = bshare[(rg*4 + ki)*64 + lane];
                bf16x8 bfr = *((bf16x8*)&u);
                acc[0][rg] = __builtin_amdgcn_mfma_f32_16x16x32_bf16(wf[0][ki], bfr, acc[0][rg], 0, 0, 0);
                acc[1][rg] = __builtin_amdgcn_mfma_f32_16x16x32_bf16(wf[1][ki], bfr, acc[1][rg], 0, 0, 0);
            }
        }
        // --- epilogue: partial e over this wave's 32 d-dims ---
        #pragma unroll
        for (int rg = 0; rg < 4; rg++){
            float ep = 0.f;
            #pragma unroll
            for (int dtL = 0; dtL < 2; dtL++){
                ep += varg[dtL][0] * tanh_fast(acc[dtL][rg][0]);
                ep += varg[dtL][1] * tanh_fast(acc[dtL][rg][1]);
                ep += varg[dtL][2] * tanh_fast(acc[dtL][rg][2]);
                ep += varg[dtL][3] * tanh_fast(acc[dtL][rg][3]);
            }
            ep += __shfl_xor(ep, 16);
            ep += __shfl_xor(ep, 32);
            if (lane < 16) epar[w][rg*16 + lane] = ep;
        }
        __syncthreads();   // epar ready + bshare consumed
        if (tid < 64){
            float e4 = epar[0][tid] + epar[1][tid] + epar[2][tid] + epar[3][tid];
            ws_e[b*NPOS + n0 + sub*64 + tid] = e4;
        }
    }
}

// KB1: partial weighted pool per (b, 256-n chunk). Softmax stats recomputed
// per block; y2 regenerated from f32 split-channel tables (stride 17, odd).
// part[(b*8+x)*128 + d] written exactly once. No atomics, no out pre-state.
__global__ __launch_bounds__(256) void kb1_pool(
        const int* __restrict__ seq, const float* __restrict__ emb,
        const float* __restrict__ cw, const float* __restrict__ cb,
        const float* __restrict__ ws_e, float* __restrict__ part)
{
    __shared__ float tblC0[3][26][17];   // ch even (c = 2g)
    __shared__ float tblC1[3][26][17];   // ch odd  (c = 2g+1)
    __shared__ int   seqw[4][260];
    __shared__ float wlds[256];
    __shared__ float red[4], red2[4];
    __shared__ float red3[4][16][8];

    int tid = threadIdx.x;
    int b = blockIdx.y;
    int x = blockIdx.x;
    int n0 = x * 256;

    for (int idx = tid; idx < 3*26*16; idx += 256){
        int k = idx / (26*16);
        int rem = idx - k*26*16;
        int l = rem >> 4;
        int cp = rem & 15;
        int c0 = cp*2;
        float v0 = 0.f, v1 = 0.f;
        #pragma unroll
        for (int i = 0; i < 5; i++){
            float e = emb[l*5 + i];
            v0 += cw[(c0*5 + i)*3 + k] * e;
            v1 += cw[((c0+1)*5 + i)*3 + k] * e;
        }
        if (k == 2){ v0 += cb[c0]; v1 += cb[c0+1]; }
        tblC0[k][l][cp] = v0;
        tblC1[k][l][cp] = v1;
    }
    const int* sb = seq + (size_t)b * LSEQ;
    for (int i = tid; i < 4*258; i += 256){
        int s = i / 258, off = i - s*258;
        seqw[s][off] = sb[s*2048 + n0 + off];
    }

    // softmax stats over the full e row
    const float* e = ws_e + b*NPOS;
    float ev[8];
    #pragma unroll
    for (int r = 0; r < 8; r++) ev[r] = e[tid + r*256];
    int wave = tid >> 6, lane = tid & 63;
    float mx = -1e30f;
    #pragma unroll
    for (int r = 0; r < 8; r++) mx = fmaxf(mx, ev[r]);
    #pragma unroll
    for (int off = 32; off >= 1; off >>= 1) mx = fmaxf(mx, __shfl_xor(mx, off));
    if (lane == 0) red[wave] = mx;
    __syncthreads();
    mx = fmaxf(fmaxf(red[0], red[1]), fmaxf(red[2], red[3]));
    float sum = 0.f;
    #pragma unroll
    for (int r = 0; r < 8; r++) sum += __expf(ev[r] - mx);
    #pragma unroll
    for (int off = 32; off >= 1; off >>= 1) sum += __shfl_xor(sum, off);
    if (lane == 0) red2[wave] = sum;
    __syncthreads();
    float rs = 1.0f / (red2[0] + red2[1] + red2[2] + red2[3]);
    wlds[tid] = __expf(e[n0 + tid] - mx) * rs;   // this chunk's weights
    __syncthreads();

    // pool: thread (g = tid&15 -> cp, nn = tid>>4) over n = it*16+nn
    int g = tid & 15, nn = tid >> 4;
    float acc[8] = {0,0,0,0,0,0,0,0};
    for (int it = 0; it < 16; it++){
        int n = it*16 + nn;
        float wgt = wlds[n];
        #pragma unroll
        for (int s = 0; s < 4; s++){
            int l0 = seqw[s][n], l1 = seqw[s][n+1], l2 = seqw[s][n+2];
            float lo = tblC0[0][l0][g] + tblC0[1][l1][g] + tblC0[2][l2][g];
            float hi = tblC1[0][l0][g] + tblC1[1][l1][g] + tblC1[2][l2][g];
            acc[s]   += wgt * fmaxf(lo, 0.f);
            acc[4+s] += wgt * fmaxf(hi, 0.f);
        }
    }
    // reduce over nn (lane bits 4,5 then cross-wave via LDS)
    #pragma unroll
    for (int j = 0; j < 8; j++){
        acc[j] += __shfl_xor(acc[j], 16);
        acc[j] += __shfl_xor(acc[j], 32);
    }
    if (lane < 16){
        #pragma unroll
        for (int j = 0; j < 8; j++) red3[wave][lane][j] = acc[j];
    }
    __syncthreads();
    if (tid < 128){
        int gg = tid >> 3, jj = tid & 7;
        part[((size_t)b*8 + x)*128 + tid] =
            red3[0][gg][jj] + red3[1][gg][jj] + red3[2][gg][jj] + red3[3][gg][jj];
    }
}

// KB2: out[b][d] = sum_x part[b][x][d] — deterministic direct store
__global__ __launch_bounds__(128) void kb2_finish(const float* __restrict__ part,
        float* __restrict__ out)
{
    int b = blockIdx.x, d = threadIdx.x;
    const float* p = part + (size_t)b*8*128 + d;
    float s = 0.f;
    #pragma unroll
    for (int x = 0; x < 8; x++) s += p[x*128];
    out[b*128 + d] = s;
}

extern "C" void kernel_launch(void* const* d_in, const int* in_sizes, int n_in,
                              void* d_out, int out_size, void* d_ws, size_t ws_size,
                              hipStream_t stream)
{
    const int*   seq = (const int*)d_in[0];
    const float* emb = (const float*)d_in[1];
    const float* cw  = (const float*)d_in[2];
    const float* cb  = (const float*)d_in[3];
    const float* Wa  = (const float*)d_in[4];
    const float* va  = (const float*)d_in[5];
    float* out = (float*)d_out;

    float* ws_e  = (float*)d_ws;                               // 128*2048 f32 = 1 MiB
    float* part  = (float*)((char*)d_ws + (size_t)1048576);    // 128*8*128 f32 = 512 KiB

    ka_conv_gemm<<<dim3(8,128), 256, 0, stream>>>(seq, emb, cw, cb, Wa, va, ws_e);
    kb1_pool    <<<dim3(8,128), 256, 0, stream>>>(seq, emb, cw, cb, ws_e, part);
    kb2_finish  <<<128,         128, 0, stream>>>(part, out);
}

// Round 8
// 118.879 us; speedup vs baseline: 1.1917x; 1.0700x over previous
//
#include <hip/hip_runtime.h>

#define B_   128
#define LSEQ 8194
#define NPOS 2048

typedef _Float16 f16x8 __attribute__((ext_vector_type(8)));
typedef _Float16 f16x2 __attribute__((ext_vector_type(2)));
typedef __attribute__((ext_vector_type(4))) float f32x4;

static __device__ __forceinline__ float tanh_fast(float x){
    float p = __expf(2.0f * x);
    float r = __builtin_amdgcn_rcpf(1.0f + p);
    return 1.0f - 2.0f * r;
}
// sum 3 packed-f16x2 taps + relu (v_pk_add_f16 + v_pk_max_f16)
static __device__ __forceinline__ unsigned h3relu(unsigned a, unsigned b, unsigned c){
    union { f16x2 h; unsigned u; } x, y, z, r;
    x.u = a; y.u = b; z.u = c;
    f16x2 s = x.h + y.h + z.h;
    f16x2 zero = { (_Float16)0.0f, (_Float16)0.0f };
    r.h = __builtin_elementwise_max(s, zero);
    return r.u;
}
static __device__ __forceinline__ unsigned hpack(float a, float b){
    union { f16x2 h; unsigned u; } pk;
    pk.h = (f16x2){ (_Float16)a, (_Float16)b };
    return pk.u;
}

// KA: fused conv + attention-GEMM -> e[b,n].
// Per block: 256 n, 4 sub-tiles of 64 rows. Wave w owns d-dims [32w,32w+32).
// Tap tables are PACKED f16 (f16x2 = channel pair), permuted so one
// ds_read_b128 per (s,tap) fetches all 4 ki x 2 channels this lane needs.
// B-frags (f16) shared across waves via 16KB LDS; MFMA f16.
__global__ __launch_bounds__(256, 4) void ka_conv_gemm(
        const int* __restrict__ seq, const float* __restrict__ emb,
        const float* __restrict__ cw, const float* __restrict__ cb,
        const float* __restrict__ Wa, const float* __restrict__ va,
        float* __restrict__ ws_e)
{
    __shared__ unsigned tblH[3][26][20];   // [tap][letter][perm pos p], p=(cp&3)*4+(cp>>2); f16x2(2cp,2cp+1)
    __shared__ int      seqw[4][260];      // 4 section windows of 258 letters
    __shared__ uint4    bshare[16*64];     // [(rg*4+ki)*64 + lane] f16 B-frags
    __shared__ float    epar[4][64];       // per-wave e partials

    int tid = threadIdx.x;
    int b   = blockIdx.y;
    int n0  = blockIdx.x * 256;

    for (int idx = tid; idx < 3*26*16; idx += 256){
        int k = idx / (26*16);
        int rem = idx - k*26*16;
        int l = rem >> 4;
        int cp = rem & 15;
        int c0 = cp*2;
        float v0 = 0.f, v1 = 0.f;
        #pragma unroll
        for (int i = 0; i < 5; i++){
            float e = emb[l*5 + i];
            v0 += cw[(c0*5 + i)*3 + k] * e;
            v1 += cw[((c0+1)*5 + i)*3 + k] * e;
        }
        if (k == 2){ v0 += cb[c0]; v1 += cb[c0+1]; }
        int p = (cp & 3)*4 + (cp >> 2);
        tblH[k][l][p] = hpack(v0, v1);
    }
    const int* sb = seq + (size_t)b * LSEQ;
    for (int i = tid; i < 4*258; i += 256){
        int s = i / 258, off = i - s*258;
        seqw[s][off] = sb[s*2048 + n0 + off];
    }

    int w = tid >> 6, lane = tid & 63;
    int m = lane & 15, q = lane >> 4;

    // wave w's W_a A-frags (f16): dt_glob=2w+dtL; lane holds W[dt_glob*16+m][ki*32+q*8+j]
    f16x8 wf[2][4];
    #pragma unroll
    for (int dtL = 0; dtL < 2; dtL++){
        #pragma unroll
        for (int ki = 0; ki < 4; ki++){
            const float* wp = Wa + ((2*w+dtL)*16 + m)*128 + ki*32 + q*8;
            f16x8 f;
            #pragma unroll
            for (int j = 0; j < 8; j++) f[j] = (_Float16)wp[j];
            wf[dtL][ki] = f;
        }
    }
    float varg[2][4];
    #pragma unroll
    for (int dtL = 0; dtL < 2; dtL++){
        #pragma unroll
        for (int r = 0; r < 4; r++)
            varg[dtL][r] = va[(2*w+dtL)*16 + q*4 + r];
    }
    __syncthreads();

    for (int sub = 0; sub < 4; sub++){
        // --- gen: wave w produces f16 B-frags for rows [sub*64 + w*16, +16) ---
        int row = sub*64 + w*16 + m;
        unsigned V[4][4];   // V[s][ki] = f16x2(chA, chB) after taps+relu
        #pragma unroll
        for (int s = 0; s < 4; s++){
            int l0 = seqw[s][row], l1 = seqw[s][row+1], l2 = seqw[s][row+2];
            uint4 t0 = *((const uint4*)&tblH[0][l0][q*4]);
            uint4 t1 = *((const uint4*)&tblH[1][l1][q*4]);
            uint4 t2 = *((const uint4*)&tblH[2][l2][q*4]);
            V[s][0] = h3relu(t0.x, t1.x, t2.x);
            V[s][1] = h3relu(t0.y, t1.y, t2.y);
            V[s][2] = h3relu(t0.z, t1.z, t2.z);
            V[s][3] = h3relu(t0.w, t1.w, t2.w);
        }
        #pragma unroll
        for (int ki = 0; ki < 4; ki++){
            uint4 o;
            o.x = __builtin_amdgcn_perm(V[1][ki], V[0][ki], 0x05040100u);  // A_s0,A_s1
            o.y = __builtin_amdgcn_perm(V[3][ki], V[2][ki], 0x05040100u);  // A_s2,A_s3
            o.z = __builtin_amdgcn_perm(V[1][ki], V[0][ki], 0x07060302u);  // B_s0,B_s1
            o.w = __builtin_amdgcn_perm(V[3][ki], V[2][ki], 0x07060302u);  // B_s2,B_s3
            bshare[(w*4 + ki)*64 + lane] = o;
        }
        __syncthreads();   // bshare ready

        // --- MFMA: wave w computes z[32w..32w+31][all 64 rows] ---
        f32x4 acc[2][4];
        #pragma unroll
        for (int dtL = 0; dtL < 2; dtL++)
            #pragma unroll
            for (int rg = 0; rg < 4; rg++) acc[dtL][rg] = (f32x4){0.f,0.f,0.f,0.f};
        #pragma unroll
        for (int rg = 0; rg < 4; rg++){
            #pragma unroll
            for (int ki = 0; ki < 4; ki++){
                union { uint4 u; f16x8 f; } bu;
                bu.u = bshare[(rg*4 + ki)*64 + lane];
                acc[0][rg] = __builtin_amdgcn_mfma_f32_16x16x32_f16(wf[0][ki], bu.f, acc[0][rg], 0, 0, 0);
                acc[1][rg] = __builtin_amdgcn_mfma_f32_16x16x32_f16(wf[1][ki], bu.f, acc[1][rg], 0, 0, 0);
            }
        }
        // --- epilogue: partial e over this wave's 32 d-dims ---
        #pragma unroll
        for (int rg = 0; rg < 4; rg++){
            float ep = 0.f;
            #pragma unroll
            for (int dtL = 0; dtL < 2; dtL++){
                ep += varg[dtL][0] * tanh_fast(acc[dtL][rg][0]);
                ep += varg[dtL][1] * tanh_fast(acc[dtL][rg][1]);
                ep += varg[dtL][2] * tanh_fast(acc[dtL][rg][2]);
                ep += varg[dtL][3] * tanh_fast(acc[dtL][rg][3]);
            }
            ep += __shfl_xor(ep, 16);
            ep += __shfl_xor(ep, 32);
            if (lane < 16) epar[w][rg*16 + lane] = ep;
        }
        __syncthreads();   // epar ready + bshare consumed
        if (tid < 64){
            float e4 = epar[0][tid] + epar[1][tid] + epar[2][tid] + epar[3][tid];
            ws_e[b*NPOS + n0 + sub*64 + tid] = e4;
        }
    }
}

// KB1: partial weighted pool per (b, 256-n chunk); y2 regenerated from
// packed-f16 tables (stride 17, odd -> all-bank spread for b32 gathers).
// part[(b*8+x)*128 + d] written exactly once. No atomics, no out pre-state.
__global__ __launch_bounds__(256) void kb1_pool(
        const int* __restrict__ seq, const float* __restrict__ emb,
        const float* __restrict__ cw, const float* __restrict__ cb,
        const float* __restrict__ ws_e, float* __restrict__ part)
{
    __shared__ unsigned tblH[3][26][17];   // f16x2(2g, 2g+1) at [tap][letter][g]
    __shared__ int      seqw[4][260];
    __shared__ float    wlds[256];
    __shared__ float    red[4], red2[4];
    __shared__ float    red3[4][16][8];

    int tid = threadIdx.x;
    int b = blockIdx.y;
    int x = blockIdx.x;
    int n0 = x * 256;

    for (int idx = tid; idx < 3*26*16; idx += 256){
        int k = idx / (26*16);
        int rem = idx - k*26*16;
        int l = rem >> 4;
        int cp = rem & 15;
        int c0 = cp*2;
        float v0 = 0.f, v1 = 0.f;
        #pragma unroll
        for (int i = 0; i < 5; i++){
            float e = emb[l*5 + i];
            v0 += cw[(c0*5 + i)*3 + k] * e;
            v1 += cw[((c0+1)*5 + i)*3 + k] * e;
        }
        if (k == 2){ v0 += cb[c0]; v1 += cb[c0+1]; }
        tblH[k][l][cp] = hpack(v0, v1);
    }
    const int* sb = seq + (size_t)b * LSEQ;
    for (int i = tid; i < 4*258; i += 256){
        int s = i / 258, off = i - s*258;
        seqw[s][off] = sb[s*2048 + n0 + off];
    }

    // softmax stats over the full e row
    const float* e = ws_e + b*NPOS;
    float ev[8];
    #pragma unroll
    for (int r = 0; r < 8; r++) ev[r] = e[tid + r*256];
    int wave = tid >> 6, lane = tid & 63;
    float mx = -1e30f;
    #pragma unroll
    for (int r = 0; r < 8; r++) mx = fmaxf(mx, ev[r]);
    #pragma unroll
    for (int off = 32; off >= 1; off >>= 1) mx = fmaxf(mx, __shfl_xor(mx, off));
    if (lane == 0) red[wave] = mx;
    __syncthreads();
    mx = fmaxf(fmaxf(red[0], red[1]), fmaxf(red[2], red[3]));
    float sum = 0.f;
    #pragma unroll
    for (int r = 0; r < 8; r++) sum += __expf(ev[r] - mx);
    #pragma unroll
    for (int off = 32; off >= 1; off >>= 1) sum += __shfl_xor(sum, off);
    if (lane == 0) red2[wave] = sum;
    __syncthreads();
    float rs = 1.0f / (red2[0] + red2[1] + red2[2] + red2[3]);
    wlds[tid] = __expf(e[n0 + tid] - mx) * rs;
    __syncthreads();

    // pool: thread (g = tid&15 -> channel pair, nn = tid>>4) over n = it*16+nn
    int g = tid & 15, nn = tid >> 4;
    float acc[8] = {0,0,0,0,0,0,0,0};
    for (int it = 0; it < 16; it++){
        int n = it*16 + nn;
        float wgt = wlds[n];
        #pragma unroll
        for (int s = 0; s < 4; s++){
            union { f16x2 h; unsigned u; } uv;
            uv.u = h3relu(tblH[0][seqw[s][n]][g],
                          tblH[1][seqw[s][n+1]][g],
                          tblH[2][seqw[s][n+2]][g]);
            acc[s]   += wgt * (float)uv.h[0];
            acc[4+s] += wgt * (float)uv.h[1];
        }
    }
    #pragma unroll
    for (int j = 0; j < 8; j++){
        acc[j] += __shfl_xor(acc[j], 16);
        acc[j] += __shfl_xor(acc[j], 32);
    }
    if (lane < 16){
        #pragma unroll
        for (int j = 0; j < 8; j++) red3[wave][lane][j] = acc[j];
    }
    __syncthreads();
    if (tid < 128){
        int gg = tid >> 3, jj = tid & 7;
        part[((size_t)b*8 + x)*128 + tid] =
            red3[0][gg][jj] + red3[1][gg][jj] + red3[2][gg][jj] + red3[3][gg][jj];
    }
}

// KB2: out[b][d] = sum_x part[b][x][d] — deterministic direct store
__global__ __launch_bounds__(128) void kb2_finish(const float* __restrict__ part,
        float* __restrict__ out)
{
    int b = blockIdx.x, d = threadIdx.x;
    const float* p = part + (size_t)b*8*128 + d;
    float s = 0.f;
    #pragma unroll
    for (int x = 0; x < 8; x++) s += p[x*128];
    out[b*128 + d] = s;
}

extern "C" void kernel_launch(void* const* d_in, const int* in_sizes, int n_in,
                              void* d_out, int out_size, void* d_ws, size_t ws_size,
                              hipStream_t stream)
{
    const int*   seq = (const int*)d_in[0];
    const float* emb = (const float*)d_in[1];
    const float* cw  = (const float*)d_in[2];
    const float* cb  = (const float*)d_in[3];
    const float* Wa  = (const float*)d_in[4];
    const float* va  = (const float*)d_in[5];
    float* out = (float*)d_out;

    float* ws_e  = (float*)d_ws;                               // 128*2048 f32 = 1 MiB
    float* part  = (float*)((char*)d_ws + (size_t)1048576);    // 128*8*128 f32 = 512 KiB

    ka_conv_gemm<<<dim3(8,128), 256, 0, stream>>>(seq, emb, cw, cb, Wa, va, ws_e);
    kb1_pool    <<<dim3(8,128), 256, 0, stream>>>(seq, emb, cw, cb, ws_e, part);
    kb2_finish  <<<128,         128, 0, stream>>>(part, out);
}

// Round 9
// 107.232 us; speedup vs baseline: 1.3211x; 1.1086x over previous
//
#include <hip/hip_runtime.h>

#define LSEQ 8194
#define NPOS 2048

typedef _Float16 f16x8 __attribute__((ext_vector_type(8)));
typedef _Float16 f16x2 __attribute__((ext_vector_type(2)));
typedef __attribute__((ext_vector_type(4))) float f32x4;

static __device__ __forceinline__ float tanh_fast(float x){
    float p = __expf(2.0f * x);
    float r = __builtin_amdgcn_rcpf(1.0f + p);
    return 1.0f - 2.0f * r;
}
// sum 3 packed-f16x2 taps + relu (v_pk_add_f16 + v_pk_max_f16)
static __device__ __forceinline__ unsigned h3relu(unsigned a, unsigned b, unsigned c){
    union { f16x2 h; unsigned u; } x, y, z, r;
    x.u = a; y.u = b; z.u = c;
    f16x2 s = x.h + y.h + z.h;
    f16x2 zero = { (_Float16)0.0f, (_Float16)0.0f };
    r.h = __builtin_elementwise_max(s, zero);
    return r.u;
}
static __device__ __forceinline__ unsigned hpack(float a, float b){
    union { f16x2 h; unsigned u; } pk;
    pk.h = (f16x2){ (_Float16)a, (_Float16)b };
    return pk.u;
}

// K0: precompute shared tables once (runs before KA/KB1, ~4 us):
//  tblp: perm-layout tap table [3][26][20] u32 (f16x2), pos p=(cp&3)*4+(cp>>2)
//  tblg: g-layout  tap table [3][26][17] u32 (f16x2)
//  wah : Wa as f16 row-major 128x128 (stored as 8192 u32 pairs)
__global__ __launch_bounds__(256) void k_tbl(
        const float* __restrict__ emb, const float* __restrict__ cw,
        const float* __restrict__ cb, const float* __restrict__ Wa,
        unsigned* __restrict__ tblp, unsigned* __restrict__ tblg,
        unsigned* __restrict__ wah)
{
    int gid = blockIdx.x*256 + threadIdx.x;
    if (gid < 1248){
        int k = gid / 416;          // 416 = 26*16
        int rem = gid - k*416;
        int l = rem >> 4;
        int cp = rem & 15;
        int c0 = cp*2;
        float v0 = 0.f, v1 = 0.f;
        #pragma unroll
        for (int i = 0; i < 5; i++){
            float e = emb[l*5 + i];
            v0 += cw[(c0*5 + i)*3 + k] * e;
            v1 += cw[((c0+1)*5 + i)*3 + k] * e;
        }
        if (k == 2){ v0 += cb[c0]; v1 += cb[c0+1]; }
        unsigned u = hpack(v0, v1);
        tblp[k*520 + l*20 + (cp & 3)*4 + (cp >> 2)] = u;
        tblg[k*442 + l*17 + cp] = u;
    }
    for (int i = gid; i < 8192; i += 1280)
        wah[i] = hpack(Wa[2*i], Wa[2*i + 1]);
}

// KA: fused conv + attention-GEMM -> e[b,n]. 128 n per block, 2 sub-tiles.
// Wave w owns d-dims [32w,32w+32). Letters staged as pre-scaled byte offsets
// (l*80, ushort); per gather = v_add + ds_read_b128. Tables/Wa loaded from ws.
__global__ __launch_bounds__(256, 4) void ka_conv_gemm(
        const int* __restrict__ seq, const unsigned* __restrict__ tblp,
        const unsigned* __restrict__ wah, const float* __restrict__ va,
        float* __restrict__ ws_e)
{
    __shared__ __align__(16) unsigned tblH[3*26*20];   // 6240 B
    __shared__ unsigned short seqw16[4][132];          // pre-scaled offsets (x80)
    __shared__ uint4 bshare[16*64];                    // 16 KB f16 B-frags
    __shared__ float epar[4][64];

    int tid = threadIdx.x;
    int b   = blockIdx.y;
    int n0  = blockIdx.x * 128;

    for (int i = tid; i < 1560; i += 256) tblH[i] = tblp[i];
    const int* sb = seq + (size_t)b * LSEQ;
    for (int i = tid; i < 4*130; i += 256){
        int s = i / 130, off = i - s*130;
        seqw16[s][off] = (unsigned short)(sb[s*2048 + n0 + off] * 80);
    }

    int w = tid >> 6, lane = tid & 63;
    int m = lane & 15, q = lane >> 4;

    // wave w's W_a A-frags (f16, pre-converted): 8 x b128 loads
    uint4 wfu[2][4];
    #pragma unroll
    for (int dtL = 0; dtL < 2; dtL++)
        #pragma unroll
        for (int ki = 0; ki < 4; ki++)
            wfu[dtL][ki] = *(const uint4*)((const char*)wah +
                ((2*w+dtL)*16 + m)*256 + ki*64 + q*16);
    float varg[2][4];
    #pragma unroll
    for (int dtL = 0; dtL < 2; dtL++)
        #pragma unroll
        for (int r = 0; r < 4; r++)
            varg[dtL][r] = va[(2*w+dtL)*16 + q*4 + r];
    __syncthreads();

    const char* tb0 = (const char*)tblH + q*16;
    const char* tb1 = tb0 + 2080;
    const char* tb2 = tb1 + 2080;

    for (int sub = 0; sub < 2; sub++){
        int row = sub*64 + w*16 + m;
        // batch all 12 letter-offset reads (independent b16 LDS loads)
        unsigned o0[4], o1[4], o2[4];
        #pragma unroll
        for (int s = 0; s < 4; s++){
            o0[s] = seqw16[s][row];
            o1[s] = seqw16[s][row+1];
            o2[s] = seqw16[s][row+2];
        }
        unsigned V[4][4];   // V[s][ki] = f16x2(chA,chB) after taps+relu
        #pragma unroll
        for (int s = 0; s < 4; s++){
            uint4 t0 = *(const uint4*)(tb0 + o0[s]);
            uint4 t1 = *(const uint4*)(tb1 + o1[s]);
            uint4 t2 = *(const uint4*)(tb2 + o2[s]);
            V[s][0] = h3relu(t0.x, t1.x, t2.x);
            V[s][1] = h3relu(t0.y, t1.y, t2.y);
            V[s][2] = h3relu(t0.z, t1.z, t2.z);
            V[s][3] = h3relu(t0.w, t1.w, t2.w);
        }
        #pragma unroll
        for (int ki = 0; ki < 4; ki++){
            uint4 o;
            o.x = __builtin_amdgcn_perm(V[1][ki], V[0][ki], 0x05040100u);  // A_s0,A_s1
            o.y = __builtin_amdgcn_perm(V[3][ki], V[2][ki], 0x05040100u);  // A_s2,A_s3
            o.z = __builtin_amdgcn_perm(V[1][ki], V[0][ki], 0x07060302u);  // B_s0,B_s1
            o.w = __builtin_amdgcn_perm(V[3][ki], V[2][ki], 0x07060302u);  // B_s2,B_s3
            bshare[(w*4 + ki)*64 + lane] = o;
        }
        __syncthreads();   // bshare ready

        f32x4 acc[2][4];
        #pragma unroll
        for (int dtL = 0; dtL < 2; dtL++)
            #pragma unroll
            for (int rg = 0; rg < 4; rg++) acc[dtL][rg] = (f32x4){0.f,0.f,0.f,0.f};
        #pragma unroll
        for (int rg = 0; rg < 4; rg++){
            #pragma unroll
            for (int ki = 0; ki < 4; ki++){
                union { uint4 u; f16x8 f; } bu, a0, a1;
                bu.u = bshare[(rg*4 + ki)*64 + lane];
                a0.u = wfu[0][ki];
                a1.u = wfu[1][ki];
                acc[0][rg] = __builtin_amdgcn_mfma_f32_16x16x32_f16(a0.f, bu.f, acc[0][rg], 0, 0, 0);
                acc[1][rg] = __builtin_amdgcn_mfma_f32_16x16x32_f16(a1.f, bu.f, acc[1][rg], 0, 0, 0);
            }
        }
        #pragma unroll
        for (int rg = 0; rg < 4; rg++){
            float ep = 0.f;
            #pragma unroll
            for (int dtL = 0; dtL < 2; dtL++){
                ep += varg[dtL][0] * tanh_fast(acc[dtL][rg][0]);
                ep += varg[dtL][1] * tanh_fast(acc[dtL][rg][1]);
                ep += varg[dtL][2] * tanh_fast(acc[dtL][rg][2]);
                ep += varg[dtL][3] * tanh_fast(acc[dtL][rg][3]);
            }
            ep += __shfl_xor(ep, 16);
            ep += __shfl_xor(ep, 32);
            if (lane < 16) epar[w][rg*16 + lane] = ep;
        }
        __syncthreads();   // epar ready + bshare consumed
        if (tid < 64){
            float e4 = epar[0][tid] + epar[1][tid] + epar[2][tid] + epar[3][tid];
            ws_e[b*NPOS + n0 + sub*64 + tid] = e4;
        }
    }
}

// KB1: partial weighted pool per (b, 256-n chunk); y2 regenerated from the
// g-layout table (loaded from ws). Letters pre-scaled (l*68, ushort).
// part[(b*8+x)*128 + d] written exactly once. No atomics, no out pre-state.
__global__ __launch_bounds__(256, 4) void kb1_pool(
        const int* __restrict__ seq, const unsigned* __restrict__ tblg,
        const float* __restrict__ ws_e, float* __restrict__ part)
{
    __shared__ unsigned tblG[3*26*17];         // 5304 B
    __shared__ unsigned short seqw16[4][260];  // pre-scaled offsets (x68)
    __shared__ float wlds[256];
    __shared__ float red[4], red2[4];
    __shared__ float red3[4][16][8];

    int tid = threadIdx.x;
    int b = blockIdx.y;
    int x = blockIdx.x;
    int n0 = x * 256;

    for (int i = tid; i < 1326; i += 256) tblG[i] = tblg[i];
    const int* sb = seq + (size_t)b * LSEQ;
    for (int i = tid; i < 4*258; i += 256){
        int s = i / 258, off = i - s*258;
        seqw16[s][off] = (unsigned short)(sb[s*2048 + n0 + off] * 68);
    }

    // softmax stats over the full e row
    const float* e = ws_e + b*NPOS;
    float ev[8];
    #pragma unroll
    for (int r = 0; r < 8; r++) ev[r] = e[tid + r*256];
    int wave = tid >> 6, lane = tid & 63;
    float mx = -1e30f;
    #pragma unroll
    for (int r = 0; r < 8; r++) mx = fmaxf(mx, ev[r]);
    #pragma unroll
    for (int off = 32; off >= 1; off >>= 1) mx = fmaxf(mx, __shfl_xor(mx, off));
    if (lane == 0) red[wave] = mx;
    __syncthreads();
    mx = fmaxf(fmaxf(red[0], red[1]), fmaxf(red[2], red[3]));
    float sum = 0.f;
    #pragma unroll
    for (int r = 0; r < 8; r++) sum += __expf(ev[r] - mx);
    #pragma unroll
    for (int off = 32; off >= 1; off >>= 1) sum += __shfl_xor(sum, off);
    if (lane == 0) red2[wave] = sum;
    __syncthreads();
    float rs = 1.0f / (red2[0] + red2[1] + red2[2] + red2[3]);
    wlds[tid] = __expf(e[n0 + tid] - mx) * rs;
    __syncthreads();

    // pool: thread (g = tid&15 -> channel pair, nn = tid>>4) over n = it*16+nn
    int g = tid & 15, nn = tid >> 4;
    const char* g0 = (const char*)tblG + g*4;
    const char* g1 = g0 + 1768;
    const char* g2 = g1 + 1768;
    float acc[8] = {0,0,0,0,0,0,0,0};
    for (int it = 0; it < 16; it++){
        int n = it*16 + nn;
        float wgt = wlds[n];
        unsigned o0[4], o1[4], o2[4];
        #pragma unroll
        for (int s = 0; s < 4; s++){
            o0[s] = seqw16[s][n];
            o1[s] = seqw16[s][n+1];
            o2[s] = seqw16[s][n+2];
        }
        #pragma unroll
        for (int s = 0; s < 4; s++){
            union { f16x2 h; unsigned u; } uv;
            uv.u = h3relu(*(const unsigned*)(g0 + o0[s]),
                          *(const unsigned*)(g1 + o1[s]),
                          *(const unsigned*)(g2 + o2[s]));
            acc[s]   += wgt * (float)uv.h[0];
            acc[4+s] += wgt * (float)uv.h[1];
        }
    }
    #pragma unroll
    for (int j = 0; j < 8; j++){
        acc[j] += __shfl_xor(acc[j], 16);
        acc[j] += __shfl_xor(acc[j], 32);
    }
    if (lane < 16){
        #pragma unroll
        for (int j = 0; j < 8; j++) red3[wave][lane][j] = acc[j];
    }
    __syncthreads();
    if (tid < 128){
        int gg = tid >> 3, jj = tid & 7;
        part[((size_t)b*8 + x)*128 + tid] =
            red3[0][gg][jj] + red3[1][gg][jj] + red3[2][gg][jj] + red3[3][gg][jj];
    }
}

// KB2: out[b][d] = sum_x part[b][x][d] — deterministic direct store
__global__ __launch_bounds__(128) void kb2_finish(const float* __restrict__ part,
        float* __restrict__ out)
{
    int b = blockIdx.x, d = threadIdx.x;
    const float* p = part + (size_t)b*8*128 + d;
    float s = 0.f;
    #pragma unroll
    for (int x = 0; x < 8; x++) s += p[x*128];
    out[b*128 + d] = s;
}

extern "C" void kernel_launch(void* const* d_in, const int* in_sizes, int n_in,
                              void* d_out, int out_size, void* d_ws, size_t ws_size,
                              hipStream_t stream)
{
    const int*   seq = (const int*)d_in[0];
    const float* emb = (const float*)d_in[1];
    const float* cw  = (const float*)d_in[2];
    const float* cb  = (const float*)d_in[3];
    const float* Wa  = (const float*)d_in[4];
    const float* va  = (const float*)d_in[5];
    float* out = (float*)d_out;

    char* wsb = (char*)d_ws;
    float*    ws_e = (float*)wsb;                            // 1 MiB
    float*    part = (float*)(wsb + (1<<20));                // 512 KiB
    unsigned* tblp = (unsigned*)(wsb + 1572864);             // 6240 B
    unsigned* tblg = (unsigned*)(wsb + 1572864 + 8192);      // 5304 B
    unsigned* wah  = (unsigned*)(wsb + 1572864 + 16384);     // 32 KiB

    k_tbl       <<<5,            256, 0, stream>>>(emb, cw, cb, Wa, tblp, tblg, wah);
    ka_conv_gemm<<<dim3(16,128), 256, 0, stream>>>(seq, tblp, wah, va, ws_e);
    kb1_pool    <<<dim3(8,128),  256, 0, stream>>>(seq, tblg, ws_e, part);
    kb2_finish  <<<128,          128, 0, stream>>>(part, out);
}